// Round 12
// baseline (995.723 us; speedup 1.0000x reference)
//
#include <hip/hip_runtime.h>

constexpr int kB  = 32;
constexpr int kNQ = 256;   // rows n
constexpr int kNT = 512;   // cols m
constexpr float kInf = 1e30f;
constexpr int kQTile = 32;    // queries per cost block
constexpr int kSlots = 30;    // LDS row-cache entries per batch
constexpr int kStride = 544;  // 8 groups x (64 data + 4 pad) floats

// ---------------------------------------------------------------------------
// Kernel 1: final_cost [B, NQ, NT]. 512 thr/block, thread == target t.
// (proven passing, bit-identical math across all passing rounds)
// ---------------------------------------------------------------------------
__global__ __launch_bounds__(512)
void cost_kernel(const float* __restrict__ trans,
                 const float* __restrict__ qpos,
                 const float* __restrict__ rot,
                 const float* __restrict__ pose,
                 float* __restrict__ cost)
{
    __shared__ float sPose[kNT * 23];   // 47104 B

    const int b     = blockIdx.x;
    const int qBase = blockIdx.y * kQTile;
    const int tid   = threadIdx.x;      // target index t

    const float* pb = pose + (size_t)b * kNT * 23;
    for (int idx = tid; idx < kNT * 23; idx += 512) sPose[idx] = pb[idx];
    __syncthreads();

    float T[23];
    #pragma unroll
    for (int d = 0; d < 23; ++d) T[d] = sPose[tid * 23 + d];

    float s = 0.f;
    #pragma unroll
    for (int d = 0; d < 23; ++d) s += fabsf(T[d]);
    const bool valid = (s > 0.f);

    const float* tr = trans + ((size_t)b * kNQ + qBase) * 3;
    const float* qp = qpos  + ((size_t)b * kNQ + qBase) * 16;
    const float* rt = rot   + ((size_t)b * kNQ + qBase) * 4;
    float* cb = cost + ((size_t)b * kNQ + qBase) * kNT + tid;

    for (int q = 0; q < kQTile; ++q) {
        const float Q0 = tr[q * 3 + 0], Q1 = tr[q * 3 + 1], Q2 = tr[q * 3 + 2];
        float a = fabsf(Q0 - T[0]);
        a += fabsf(Q1 - T[1]);
        a += fabsf(Q2 - T[2]);
        float bsum = 0.f;
        #pragma unroll
        for (int d = 0; d < 16; ++d) bsum += fabsf(qp[q * 16 + d] - T[3 + d]);
        const float r0 = rt[q * 4 + 0], r1 = rt[q * 4 + 1];
        const float r2 = rt[q * 4 + 2], r3 = rt[q * 4 + 3];
        float dot = r0 * T[19] + r1 * T[20] + r2 * T[21] + r3 * T[22];
        float c = (a + bsum) + (1.0f - fabsf(dot));
        cb[(size_t)q * kNT] = valid ? c : kInf;
    }
}

// Wave64 min-reduction via DPP (rocPRIM pattern). All inputs are non-negative
// float bit-patterns (incl +inf sentinel), so u32 order == f32 order.
__device__ __forceinline__ unsigned wave_min_u32(unsigned x) {
    unsigned t;
    t = (unsigned)__builtin_amdgcn_update_dpp((int)0xFFFFFFFF, (int)x, 0x111, 0xF, 0xF, false); x = t < x ? t : x; // row_shr:1
    t = (unsigned)__builtin_amdgcn_update_dpp((int)0xFFFFFFFF, (int)x, 0x112, 0xF, 0xF, false); x = t < x ? t : x; // row_shr:2
    t = (unsigned)__builtin_amdgcn_update_dpp((int)0xFFFFFFFF, (int)x, 0x114, 0xF, 0xF, false); x = t < x ? t : x; // row_shr:4
    t = (unsigned)__builtin_amdgcn_update_dpp((int)0xFFFFFFFF, (int)x, 0x118, 0xF, 0xF, false); x = t < x ? t : x; // row_shr:8
    t = (unsigned)__builtin_amdgcn_update_dpp((int)0xFFFFFFFF, (int)x, 0x142, 0xF, 0xF, false); x = t < x ? t : x; // row_bcast:15
    t = (unsigned)__builtin_amdgcn_update_dpp((int)0xFFFFFFFF, (int)x, 0x143, 0xF, 0xF, false); x = t < x ? t : x; // row_bcast:31
    return (unsigned)__builtin_amdgcn_readlane((int)x, 63);
}

// ---------------------------------------------------------------------------
// Kernel 2: JV LSAP — R11's per-batch numerics VERBATIM (v=0, u=row-min,
// greedy argmin match; wave-0 SAP; unmasked packed relax + frozen-at-sweep
// state; DPP u32 min + ballot lowest-lane tie-break; padded AoS row cache).
// R12: ONE SCHEDULING CHANGE — each block's wave 0 interleaves TWO batches
// as a 2-stage software pipeline: a batch's step ends by issuing its next
// row load; the other batch's ~200-cyc VALU step hides that latency.
// Cache insert deferred to the consume point (so the miss-path store never
// forces an early vmcnt wait). Free rows precomputed into a static ordered
// list (augmentation never unmatches a row). No fp change whatsoever.
// ---------------------------------------------------------------------------
__global__ __launch_bounds__(256)
void hungarian_kernel(const float* __restrict__ cost,
                      float* __restrict__ outInds,
                      float* __restrict__ outMask)
{
    __shared__ float rowCache[2][kSlots * kStride];  // 2 x 65280 B
    __shared__ float u[2][kNQ];
    __shared__ int   col4row[2][kNQ];
    __shared__ int   row4col[2][kNT];
    __shared__ int   pathL[2][kNT];
    __shared__ int   colBest[2][kNT];
    __shared__ int   rowArg[2][kNQ];
    __shared__ int   freeList[2][kNQ];
    __shared__ unsigned long long fmask[2][4];
    __shared__ int   nFreeS[2];

    const int blk = blockIdx.x;          // 0..15, handles batches 2*blk, 2*blk+1
    const int tid = threadIdx.x;
    const int wv  = tid >> 6, ln = tid & 63;

    // ---- Phase A (both batches): row minima + greedy match + free list ----
    for (int s = 0; s < 2; ++s) {
        const float* C = cost + (size_t)(blk * 2 + s) * kNQ * kNT;
        {
            const float4* Crow = (const float4*)(C + (size_t)tid * kNT);
            float bm = kInf; int barg = 0;
            #pragma unroll 4
            for (int j4 = 0; j4 < kNT / 4; ++j4) {
                float4 cc = Crow[j4];
                const int jb = j4 * 4;
                if (cc.x < bm) { bm = cc.x; barg = jb + 0; }
                if (cc.y < bm) { bm = cc.y; barg = jb + 1; }
                if (cc.z < bm) { bm = cc.z; barg = jb + 2; }
                if (cc.w < bm) { bm = cc.w; barg = jb + 3; }
            }
            u[s][tid] = bm;            // matched slack exactly 0; feasible sign-exact
            rowArg[s][tid] = barg;
            col4row[s][tid] = -1;
        }
        row4col[s][tid] = -1;           row4col[s][tid + 256] = -1;
        colBest[s][tid] = 0x7fffffff;   colBest[s][tid + 256] = 0x7fffffff;
        __syncthreads();
        atomicMin(&colBest[s][rowArg[s][tid]], tid);
        __syncthreads();
        {
            const int j = rowArg[s][tid];
            if (colBest[s][j] == tid) { col4row[s][tid] = j; row4col[s][j] = tid; }
        }
        __syncthreads();
        {
            const bool f = col4row[s][tid] < 0;
            const unsigned long long m = __ballot(f);
            if (ln == 0) fmask[s][wv] = m;
            __syncthreads();
            int base = 0;
            for (int w = 0; w < wv; ++w) base += __popcll(fmask[s][w]);
            if (f) freeList[s][base + __popcll(m & ((1ull << ln) - 1ull))] = tid;
            if (tid == 0)
                nFreeS[s] = __popcll(fmask[s][0]) + __popcll(fmask[s][1])
                          + __popcll(fmask[s][2]) + __popcll(fmask[s][3]);
            __syncthreads();
        }
    }

    // ---- Phase C: interleaved dual-batch SAP, wave 0 only ----
    if (tid < 64) {
        const int lane = tid;
        const int laneOff = (lane >> 3) * 68 + (lane & 7) * 8;
        typedef float v2f __attribute__((ext_vector_type(2)));

        const float* Cb[2] = { cost + (size_t)(blk * 2 + 0) * kNQ * kNT,
                               cost + (size_t)(blk * 2 + 1) * kNQ * kNT };

        // per-batch per-lane state
        float vRa[2][8], spc[2][8], mskA[2][8], frzV[2][8];
        int   pth[2][8], frzP[2][8];
        unsigned scM[2];
        int   tag[2] = { -1, -1 }, rr[2] = { 0, 0 };
        bool  pend[2] = { false, false };
        int   pendSlot[2] = { 0, 0 };
        float4 pA[2], pB[2];
        float uiC[2];
        // wave-uniform per-batch scalars
        bool done[2] = { false, false }, act[2] = { false, false };
        int  frI[2] = { 0, 0 }, curR[2] = { -1, -1 }, iR[2] = { -1, -1 };
        float mvR[2] = { 0.f, 0.f };
        const int nF[2] = { nFreeS[0], nFreeS[1] };
        #pragma unroll
        for (int c = 0; c < 8; ++c) { vRa[0][c] = 0.f; vRa[1][c] = 0.f; }

        // issue the row fetch for batch s, row i (no waits forced here)
        auto issue = [&](int s, int i, bool allowIns) {
            uiC[s] = u[s][i];
            const unsigned long long hm = __ballot(tag[s] == i);
            if (hm != 0ull) {                 // cache hit (wave-uniform)
                const int slot = (int)__ffsll(hm) - 1;
                const float4* lp = (const float4*)&rowCache[s][slot * kStride + laneOff];
                pA[s] = lp[0]; pB[s] = lp[1];
            } else {                          // miss: global (L2) load
                const float4* rp = (const float4*)(Cb[s] + (size_t)i * kNT + lane * 8);
                pA[s] = rp[0]; pB[s] = rp[1];
                if (allowIns) {               // reserve slot now, write at consume
                    pend[s] = true; pendSlot[s] = rr[s];
                    if (lane == rr[s]) tag[s] = i;
                    rr[s] = rr[s] + 1; if (rr[s] == kSlots) rr[s] = 0;
                }
            }
        };

        // begin next search for batch s (or mark done)
        auto start = [&](int s) {
            if (frI[s] >= nF[s]) { done[s] = true; return; }
            curR[s] = freeList[s][frI[s]++];
            #pragma unroll
            for (int c = 0; c < 8; ++c) {
                spc[s][c] = kInf; pth[s][c] = -1; mskA[s][c] = 0.f;
                frzV[s][c] = 0.f; frzP[s][c] = -1;
            }
            scM[s] = 0; mvR[s] = 0.f; iR[s] = curR[s];
            issue(s, iR[s], false);           // cur rows are one-shot: no insert
            act[s] = true;
        };

        // consume in-flight row, do one expansion (verbatim R11 numerics)
        auto step = [&](int s) {
            if (pend[s]) {                    // deferred cache insert
                float4* wp = (float4*)&rowCache[s][pendSlot[s] * kStride + laneOff];
                wp[0] = pA[s]; wp[1] = pB[s];
                pend[s] = false;
            }
            const float4 p0 = pA[s], p1 = pB[s];
            const float ui = uiC[s];
            const float minVal = mvR[s];
            const int   i = iR[s];

            // ---- UNMASKED packed relax (value-exact op order) ----
            const v2f cc2[4] = { {p0.x, p0.y}, {p0.z, p0.w},
                                 {p1.x, p1.y}, {p1.z, p1.w} };
            const v2f mv2 = { minVal, minVal };
            const v2f ui2 = { ui, ui };
            float r8[8];
            #pragma unroll
            for (int p = 0; p < 4; ++p) {
                const v2f vv = { vRa[s][2*p], vRa[s][2*p + 1] };
                const v2f rp2 = ((mv2 + cc2[p]) - ui2) - vv;
                r8[2*p] = rp2.x; r8[2*p + 1] = rp2.y;
            }
            #pragma unroll
            for (int c = 0; c < 8; ++c) {
                const bool lt = r8[c] < spc[s][c];
                spc[s][c] = lt ? r8[c] : spc[s][c];
                pth[s][c] = lt ? i : pth[s][c];
            }

            // ---- masked local argmin: msk = spc + {0|+inf}, u32 tree ----
            float mskv[8];
            #pragma unroll
            for (int p = 0; p < 4; ++p) {
                const v2f s2 = { spc[s][2*p], spc[s][2*p + 1] };
                const v2f a2 = { mskA[s][2*p], mskA[s][2*p + 1] };
                const v2f m2 = s2 + a2;
                mskv[2*p] = m2.x; mskv[2*p + 1] = m2.y;
            }
            unsigned sp[8];
            #pragma unroll
            for (int c = 0; c < 8; ++c) sp[c] = __float_as_uint(mskv[c]);
            unsigned mA = sp[1] < sp[0] ? sp[1] : sp[0]; int aA = sp[1] < sp[0] ? 1 : 0;
            unsigned mB = sp[3] < sp[2] ? sp[3] : sp[2]; int aB = sp[3] < sp[2] ? 3 : 2;
            unsigned mC = sp[5] < sp[4] ? sp[5] : sp[4]; int aC = sp[5] < sp[4] ? 5 : 4;
            unsigned mD = sp[7] < sp[6] ? sp[7] : sp[6]; int aD = sp[7] < sp[6] ? 7 : 6;
            unsigned mAB = mB < mA ? mB : mA; int aAB = mB < mA ? aB : aA;
            unsigned mCD = mD < mC ? mD : mC; int aCD = mD < mC ? aD : aC;
            unsigned lvu = mCD < mAB ? mCD : mAB; int lc = mCD < mAB ? aCD : aAB;
            const int lix  = lane * 8 + lc;
            const int spec = row4col[s][lix];        // speculative owner prefetch

            const unsigned gmu = wave_min_u32(lvu);
            const unsigned long long bal = __ballot(lvu == gmu);
            const int wl    = (int)__ffsll(bal) - 1;
            const int jstar = __builtin_amdgcn_readlane(lix, wl);
            const int own   = __builtin_amdgcn_readlane(spec, wl);
            const float mv  = __uint_as_float(gmu);
            mvR[s] = mv;

            if (wl == lane) {                 // freeze sweep-time state
                const int lcw = jstar & 7;
                scM[s] |= 1u << lcw;
                #pragma unroll
                for (int c = 0; c < 8; ++c) {
                    if (c == lcw) {
                        mskA[s][c] = __builtin_inff();
                        frzV[s][c] = mv;      // == spc at sweep time
                        frzP[s][c] = pth[s][c];
                    }
                }
            }

            if (own < 0) {
                // ---- finish: dual updates + augment (sweep-time values) ----
                if (lane == 0) u[s][curR[s]] += mv;
                #pragma unroll
                for (int c = 0; c < 8; ++c) {
                    if ((scM[s] >> c) & 1u) {
                        const int j = lane * 8 + c;
                        const int r = row4col[s][j];
                        const float d = mv - frzV[s][c];
                        if (r >= 0) u[s][r] += d;     // owners distinct
                        vRa[s][c] -= d;
                        pathL[s][j] = frzP[s][c];
                    }
                }
                __threadfence_block();
                if (lane == 0) {
                    int j = jstar;
                    while (true) {
                        const int pi = pathL[s][j];
                        row4col[s][j] = pi;
                        const int nj = col4row[s][pi];
                        col4row[s][pi] = j;
                        if (pi == curR[s]) break;
                        j = nj;
                    }
                }
                __threadfence_block();
                act[s] = false;
            } else {
                iR[s] = own;
                issue(s, own, true);          // next load in flight during other batch's step
            }
        };

        for (int tick = 0; tick < 400000 && !(done[0] && done[1]); ++tick) {
            if (!done[0]) { if (!act[0]) start(0); else step(0); }
            if (!done[1]) { if (!act[1]) start(1); else step(1); }
        }
    }
    __syncthreads();

    #pragma unroll
    for (int s = 0; s < 2; ++s) {
        const int b = blk * 2 + s;
        outInds[(size_t)b * kNQ + tid] = (float)col4row[s][tid];
        outMask[(size_t)b * kNQ + tid] = 1.0f;
    }
}

extern "C" void kernel_launch(void* const* d_in, const int* in_sizes, int n_in,
                              void* d_out, int out_size, void* d_ws, size_t ws_size,
                              hipStream_t stream) {
    const float* trans = (const float*)d_in[0];
    const float* qpos  = (const float*)d_in[1];
    const float* rot   = (const float*)d_in[2];
    const float* pose  = (const float*)d_in[3];

    float* out  = (float*)d_out;
    float* cost = out;
    float* inds = out + (size_t)kB * kNQ * kNT;
    float* mask = inds + (size_t)kB * kNQ;

    dim3 g1(kB, kNQ / kQTile);
    cost_kernel<<<g1, 512, 0, stream>>>(trans, qpos, rot, pose, cost);
    hungarian_kernel<<<kB / 2, 256, 0, stream>>>(cost, inds, mask);
}

// Round 13
// 571.203 us; speedup vs baseline: 1.7432x; 1.7432x over previous
//
#include <hip/hip_runtime.h>

constexpr int kB  = 32;
constexpr int kNQ = 256;   // rows n
constexpr int kNT = 512;   // cols m
constexpr float kInf = 1e30f;
constexpr int kQTile = 32;   // queries per cost block
constexpr int kWPB   = 8;    // waves (= batches) per hungarian block

// ---------------------------------------------------------------------------
// Kernel 1: final_cost [B, NQ, NT]. 512 thr/block, thread == target t.
// (proven passing, bit-identical math across all passing rounds)
// ---------------------------------------------------------------------------
__global__ __launch_bounds__(512)
void cost_kernel(const float* __restrict__ trans,
                 const float* __restrict__ qpos,
                 const float* __restrict__ rot,
                 const float* __restrict__ pose,
                 float* __restrict__ cost)
{
    __shared__ float sPose[kNT * 23];   // 47104 B

    const int b     = blockIdx.x;
    const int qBase = blockIdx.y * kQTile;
    const int tid   = threadIdx.x;      // target index t

    const float* pb = pose + (size_t)b * kNT * 23;
    for (int idx = tid; idx < kNT * 23; idx += 512) sPose[idx] = pb[idx];
    __syncthreads();

    float T[23];
    #pragma unroll
    for (int d = 0; d < 23; ++d) T[d] = sPose[tid * 23 + d];

    float s = 0.f;
    #pragma unroll
    for (int d = 0; d < 23; ++d) s += fabsf(T[d]);
    const bool valid = (s > 0.f);

    const float* tr = trans + ((size_t)b * kNQ + qBase) * 3;
    const float* qp = qpos  + ((size_t)b * kNQ + qBase) * 16;
    const float* rt = rot   + ((size_t)b * kNQ + qBase) * 4;
    float* cb = cost + ((size_t)b * kNQ + qBase) * kNT + tid;

    for (int q = 0; q < kQTile; ++q) {
        const float Q0 = tr[q * 3 + 0], Q1 = tr[q * 3 + 1], Q2 = tr[q * 3 + 2];
        float a = fabsf(Q0 - T[0]);
        a += fabsf(Q1 - T[1]);
        a += fabsf(Q2 - T[2]);
        float bsum = 0.f;
        #pragma unroll
        for (int d = 0; d < 16; ++d) bsum += fabsf(qp[q * 16 + d] - T[3 + d]);
        const float r0 = rt[q * 4 + 0], r1 = rt[q * 4 + 1];
        const float r2 = rt[q * 4 + 2], r3 = rt[q * 4 + 3];
        float dot = r0 * T[19] + r1 * T[20] + r2 * T[21] + r3 * T[22];
        float c = (a + bsum) + (1.0f - fabsf(dot));
        cb[(size_t)q * kNT] = valid ? c : kInf;
    }
}

// Wave64 min-reduction via DPP (rocPRIM pattern). All inputs are non-negative
// float bit-patterns (incl +inf sentinel), so u32 order == f32 order.
__device__ __forceinline__ unsigned wave_min_u32(unsigned x) {
    unsigned t;
    t = (unsigned)__builtin_amdgcn_update_dpp((int)0xFFFFFFFF, (int)x, 0x111, 0xF, 0xF, false); x = t < x ? t : x; // row_shr:1
    t = (unsigned)__builtin_amdgcn_update_dpp((int)0xFFFFFFFF, (int)x, 0x112, 0xF, 0xF, false); x = t < x ? t : x; // row_shr:2
    t = (unsigned)__builtin_amdgcn_update_dpp((int)0xFFFFFFFF, (int)x, 0x114, 0xF, 0xF, false); x = t < x ? t : x; // row_shr:4
    t = (unsigned)__builtin_amdgcn_update_dpp((int)0xFFFFFFFF, (int)x, 0x118, 0xF, 0xF, false); x = t < x ? t : x; // row_shr:8
    t = (unsigned)__builtin_amdgcn_update_dpp((int)0xFFFFFFFF, (int)x, 0x142, 0xF, 0xF, false); x = t < x ? t : x; // row_bcast:15
    t = (unsigned)__builtin_amdgcn_update_dpp((int)0xFFFFFFFF, (int)x, 0x143, 0xF, 0xF, false); x = t < x ? t : x; // row_bcast:31
    return (unsigned)__builtin_amdgcn_readlane((int)x, 63);
}

// ---------------------------------------------------------------------------
// Kernel 2: JV LSAP — R11's per-batch numerics VERBATIM (v=0, u=row-min,
// greedy argmin match; SAP with unmasked packed relax + frozen-at-sweep
// state; DPP u32 min + ballot lowest-lane tie-break; speculative row4col
// prefetch). R13: HW-scheduled overlap — 8 waves per block, one batch per
// wave (4 blocks x 8 = 32 batches). Each SIMD hosts 2 independent chains;
// the wave scheduler hides one chain's L2 latency behind the other's VALU
// (m114 mechanism). No LDS row cache (L2 direct). Phase A per-wave: lane
// owns 4 rows, same per-row scan order (bit-identical u/rowArg); greedy
// match via same atomicMin-on-row-index (order-independent).
// ---------------------------------------------------------------------------
__global__ __launch_bounds__(512)
void hungarian_kernel(const float* __restrict__ cost,
                      float* __restrict__ outInds,
                      float* __restrict__ outMask)
{
    __shared__ float u[kWPB][kNQ];
    __shared__ int   col4row[kWPB][kNQ];
    __shared__ int   row4col[kWPB][kNT];
    __shared__ int   pathL[kWPB][kNT];
    __shared__ int   colBest[kWPB][kNT];
    __shared__ int   rowArg[kWPB][kNQ];   // total 73,728 B

    const int tid  = threadIdx.x;
    const int w    = tid >> 6;           // wave index = batch slot
    const int lane = tid & 63;
    const int b    = blockIdx.x * kWPB + w;
    const float* __restrict__ C = cost + (size_t)b * kNQ * kNT;

    // ---- Phase A: row minima + greedy matching (lane owns rows 4l..4l+3) ----
    #pragma unroll
    for (int k = 0; k < 4; ++k) {
        const int r = lane * 4 + k;
        const float4* Crow = (const float4*)(C + (size_t)r * kNT);
        float bm = kInf; int barg = 0;
        #pragma unroll 4
        for (int j4 = 0; j4 < kNT / 4; ++j4) {
            float4 cc = Crow[j4];
            const int jb = j4 * 4;
            if (cc.x < bm) { bm = cc.x; barg = jb + 0; }
            if (cc.y < bm) { bm = cc.y; barg = jb + 1; }
            if (cc.z < bm) { bm = cc.z; barg = jb + 2; }
            if (cc.w < bm) { bm = cc.w; barg = jb + 3; }
        }
        u[w][r] = bm;      // matched slack exactly 0; feasible sign-exact
        rowArg[w][r] = barg;
        col4row[w][r] = -1;
    }
    #pragma unroll
    for (int k = 0; k < 8; ++k) {
        row4col[w][lane * 8 + k] = -1;
        colBest[w][lane * 8 + k] = 0x7fffffff;
    }
    __syncthreads();
    #pragma unroll
    for (int k = 0; k < 4; ++k) {
        const int r = lane * 4 + k;
        atomicMin(&colBest[w][rowArg[w][r]], r);
    }
    __syncthreads();
    #pragma unroll
    for (int k = 0; k < 4; ++k) {
        const int r = lane * 4 + k;
        const int j = rowArg[w][r];
        if (colBest[w][j] == r) { col4row[w][r] = j; row4col[w][j] = r; }
    }
    __syncthreads();

    // ---- Phase C: SAP, one wave per batch (wave-synchronous, no barriers) ----
    {
        typedef float v2f __attribute__((ext_vector_type(2)));
        float vR[8];
        #pragma unroll
        for (int c = 0; c < 8; ++c) vR[c] = 0.f;

        for (int cur = 0; cur < kNQ; ++cur) {
            if (col4row[w][cur] >= 0) continue;   // wave-uniform

            float spcR[8]; int pathR[8]; float mskA[8]; float frzV[8]; int frzP[8];
            #pragma unroll
            for (int c = 0; c < 8; ++c) {
                spcR[c] = kInf; pathR[c] = -1; mskA[c] = 0.f;
                frzV[c] = 0.f;  frzP[c] = -1;
            }
            unsigned scMask = 0;

            int   i      = cur;
            float minVal = 0.f;
            int   sink   = -1;

            for (int guard = 0; guard < kNT + 2 && sink < 0; ++guard) {
                const float ui = u[w][i];         // LDS read, overlaps row fetch
                const float4* rp = (const float4*)(C + (size_t)i * kNT + lane * 8);
                const float4 p0 = rp[0], p1 = rp[1];

                // ---- UNMASKED packed relax (value-exact op order) ----
                const v2f cc2[4] = { {p0.x, p0.y}, {p0.z, p0.w},
                                     {p1.x, p1.y}, {p1.z, p1.w} };
                const v2f mv2 = { minVal, minVal };
                const v2f ui2 = { ui, ui };
                float r8[8];
                #pragma unroll
                for (int p = 0; p < 4; ++p) {
                    const v2f vv = { vR[2*p], vR[2*p + 1] };
                    const v2f rp2 = ((mv2 + cc2[p]) - ui2) - vv;
                    r8[2*p] = rp2.x; r8[2*p + 1] = rp2.y;
                }
                #pragma unroll
                for (int c = 0; c < 8; ++c) {
                    const bool lt = r8[c] < spcR[c];
                    spcR[c]  = lt ? r8[c] : spcR[c];
                    pathR[c] = lt ? i : pathR[c];
                }

                // ---- masked local argmin: msk = spc + {0|+inf}, u32 tree ----
                float mskv[8];
                #pragma unroll
                for (int p = 0; p < 4; ++p) {
                    const v2f s2 = { spcR[2*p], spcR[2*p + 1] };
                    const v2f a2 = { mskA[2*p], mskA[2*p + 1] };
                    const v2f m2 = s2 + a2;
                    mskv[2*p] = m2.x; mskv[2*p + 1] = m2.y;
                }
                unsigned sp[8];
                #pragma unroll
                for (int c = 0; c < 8; ++c) sp[c] = __float_as_uint(mskv[c]);
                unsigned mA = sp[1] < sp[0] ? sp[1] : sp[0]; int aA = sp[1] < sp[0] ? 1 : 0;
                unsigned mB = sp[3] < sp[2] ? sp[3] : sp[2]; int aB = sp[3] < sp[2] ? 3 : 2;
                unsigned mC = sp[5] < sp[4] ? sp[5] : sp[4]; int aC = sp[5] < sp[4] ? 5 : 4;
                unsigned mD = sp[7] < sp[6] ? sp[7] : sp[6]; int aD = sp[7] < sp[6] ? 7 : 6;
                unsigned mAB = mB < mA ? mB : mA; int aAB = mB < mA ? aB : aA;
                unsigned mCD = mD < mC ? mD : mC; int aCD = mD < mC ? aD : aC;
                unsigned lvu = mCD < mAB ? mCD : mAB; int lc = mCD < mAB ? aCD : aAB;
                const int lix  = lane * 8 + lc;
                const int spec = row4col[w][lix];     // speculative owner prefetch

                const unsigned gmu = wave_min_u32(lvu);
                const unsigned long long bal = __ballot(lvu == gmu);
                const int wl    = (int)__ffsll(bal) - 1;
                const int jstar = __builtin_amdgcn_readlane(lix, wl);
                const int own   = __builtin_amdgcn_readlane(spec, wl);
                minVal = __uint_as_float(gmu);

                if (own < 0) sink = jstar;
                else         i    = own;

                if (wl == lane) {                 // freeze sweep-time state
                    const int lcw = jstar & 7;
                    scMask |= 1u << lcw;
                    #pragma unroll
                    for (int c = 0; c < 8; ++c) {
                        if (c == lcw) {
                            mskA[c] = __builtin_inff();
                            frzV[c] = minVal;     // == spcR[c] at sweep time
                            frzP[c] = pathR[c];
                        }
                    }
                }
            }

            // ---- dual updates (sweep-time values, per swept column) ----
            if (lane == 0) u[w][cur] += minVal;
            #pragma unroll
            for (int c = 0; c < 8; ++c) {
                if ((scMask >> c) & 1u) {
                    const int j = lane * 8 + c;
                    const int r = row4col[w][j];
                    const float d = minVal - frzV[c];
                    if (r >= 0) u[w][r] += d;     // owners distinct (matching)
                    vR[c] -= d;
                    pathL[w][j] = frzP[c];
                }
            }
            __threadfence_block();

            // ---- augment along alternating path (lane 0) ----
            if (lane == 0 && sink >= 0) {
                int j = sink;
                while (true) {
                    const int pi = pathL[w][j];
                    row4col[w][j] = pi;
                    const int nj = col4row[w][pi];
                    col4row[w][pi] = j;
                    if (pi == cur) break;
                    j = nj;
                }
            }
            __threadfence_block();
        }
    }

    // ---- output (wave-local, no barrier needed) ----
    #pragma unroll
    for (int k = 0; k < 4; ++k) {
        const int r = lane * 4 + k;
        outInds[(size_t)b * kNQ + r] = (float)col4row[w][r];
        outMask[(size_t)b * kNQ + r] = 1.0f;
    }
}

extern "C" void kernel_launch(void* const* d_in, const int* in_sizes, int n_in,
                              void* d_out, int out_size, void* d_ws, size_t ws_size,
                              hipStream_t stream) {
    const float* trans = (const float*)d_in[0];
    const float* qpos  = (const float*)d_in[1];
    const float* rot   = (const float*)d_in[2];
    const float* pose  = (const float*)d_in[3];

    float* out  = (float*)d_out;
    float* cost = out;
    float* inds = out + (size_t)kB * kNQ * kNT;
    float* mask = inds + (size_t)kB * kNQ;

    dim3 g1(kB, kNQ / kQTile);
    cost_kernel<<<g1, 512, 0, stream>>>(trans, qpos, rot, pose, cost);
    hungarian_kernel<<<kB / kWPB, 512, 0, stream>>>(cost, inds, mask);
}

// Round 14
// 453.127 us; speedup vs baseline: 2.1975x; 1.2606x over previous
//
#include <hip/hip_runtime.h>

constexpr int kB  = 32;
constexpr int kNQ = 256;   // rows n
constexpr int kNT = 512;   // cols m
constexpr float kInf = 1e30f;
constexpr int kQTile = 32;    // queries per cost block
constexpr int kSlots = 56;    // LDS row-cache entries
constexpr int kStride = 544;  // 8 groups x (64 data + 4 pad) floats

// ---------------------------------------------------------------------------
// Kernel 1: final_cost [B, NQ, NT]. 512 thr/block, thread == target t.
// (proven passing, bit-identical math across all passing rounds)
// ---------------------------------------------------------------------------
__global__ __launch_bounds__(512)
void cost_kernel(const float* __restrict__ trans,
                 const float* __restrict__ qpos,
                 const float* __restrict__ rot,
                 const float* __restrict__ pose,
                 float* __restrict__ cost)
{
    __shared__ float sPose[kNT * 23];   // 47104 B

    const int b     = blockIdx.x;
    const int qBase = blockIdx.y * kQTile;
    const int tid   = threadIdx.x;      // target index t

    const float* pb = pose + (size_t)b * kNT * 23;
    for (int idx = tid; idx < kNT * 23; idx += 512) sPose[idx] = pb[idx];
    __syncthreads();

    float T[23];
    #pragma unroll
    for (int d = 0; d < 23; ++d) T[d] = sPose[tid * 23 + d];

    float s = 0.f;
    #pragma unroll
    for (int d = 0; d < 23; ++d) s += fabsf(T[d]);
    const bool valid = (s > 0.f);

    const float* tr = trans + ((size_t)b * kNQ + qBase) * 3;
    const float* qp = qpos  + ((size_t)b * kNQ + qBase) * 16;
    const float* rt = rot   + ((size_t)b * kNQ + qBase) * 4;
    float* cb = cost + ((size_t)b * kNQ + qBase) * kNT + tid;

    for (int q = 0; q < kQTile; ++q) {
        const float Q0 = tr[q * 3 + 0], Q1 = tr[q * 3 + 1], Q2 = tr[q * 3 + 2];
        float a = fabsf(Q0 - T[0]);
        a += fabsf(Q1 - T[1]);
        a += fabsf(Q2 - T[2]);
        float bsum = 0.f;
        #pragma unroll
        for (int d = 0; d < 16; ++d) bsum += fabsf(qp[q * 16 + d] - T[3 + d]);
        const float r0 = rt[q * 4 + 0], r1 = rt[q * 4 + 1];
        const float r2 = rt[q * 4 + 2], r3 = rt[q * 4 + 3];
        float dot = r0 * T[19] + r1 * T[20] + r2 * T[21] + r3 * T[22];
        float c = (a + bsum) + (1.0f - fabsf(dot));
        cb[(size_t)q * kNT] = valid ? c : kInf;
    }
}

// Wave64 min-reduction via DPP (rocPRIM pattern). All inputs are non-negative
// float bit-patterns (incl +inf sentinel), so u32 order == f32 order.
__device__ __forceinline__ unsigned wave_min_u32(unsigned x) {
    unsigned t;
    t = (unsigned)__builtin_amdgcn_update_dpp((int)0xFFFFFFFF, (int)x, 0x111, 0xF, 0xF, false); x = t < x ? t : x; // row_shr:1
    t = (unsigned)__builtin_amdgcn_update_dpp((int)0xFFFFFFFF, (int)x, 0x112, 0xF, 0xF, false); x = t < x ? t : x; // row_shr:2
    t = (unsigned)__builtin_amdgcn_update_dpp((int)0xFFFFFFFF, (int)x, 0x114, 0xF, 0xF, false); x = t < x ? t : x; // row_shr:4
    t = (unsigned)__builtin_amdgcn_update_dpp((int)0xFFFFFFFF, (int)x, 0x118, 0xF, 0xF, false); x = t < x ? t : x; // row_shr:8
    t = (unsigned)__builtin_amdgcn_update_dpp((int)0xFFFFFFFF, (int)x, 0x142, 0xF, 0xF, false); x = t < x ? t : x; // row_bcast:15
    t = (unsigned)__builtin_amdgcn_update_dpp((int)0xFFFFFFFF, (int)x, 0x143, 0xF, 0xF, false); x = t < x ? t : x; // row_bcast:31
    return (unsigned)__builtin_amdgcn_readlane((int)x, 63);
}

// ---------------------------------------------------------------------------
// Kernel 2: JV LSAP — R11 VERBATIM numerics (v=0, u=row-min, greedy argmin
// match; wave-0 SAP; unmasked packed relax + frozen-at-sweep state; DPP u32
// min + ballot lowest-lane tie-break; padded AoS LDS row cache).
// R14 micro-trims (value-exact):
//  - (spec+1)<<16 | lix packed -> ONE v_readlane instead of two.
//  - cur rows (guard==0) ARE inserted into the cache: a free row becomes
//    matched after its search and is re-expanded by later searches.
// ---------------------------------------------------------------------------
__global__ __launch_bounds__(256)
void hungarian_kernel(const float* __restrict__ cost,
                      float* __restrict__ outInds,
                      float* __restrict__ outMask)
{
    __shared__ float rowCache[kSlots * kStride];  // 121856 B
    __shared__ float u[kNQ];
    __shared__ int   col4row[kNQ];
    __shared__ int   row4col[kNT];
    __shared__ int   colBest[kNT];
    __shared__ int   pathL[kNT];
    __shared__ int   rowArg[kNQ];

    const int b   = blockIdx.x;
    const int tid = threadIdx.x;
    const float* __restrict__ C = cost + (size_t)b * kNQ * kNT;

    // ---- Phase A: row minima + greedy matching (thread t == row t) ----
    {
        const float4* Crow = (const float4*)(C + (size_t)tid * kNT);
        float bm = kInf; int barg = 0;
        #pragma unroll 4
        for (int j4 = 0; j4 < kNT / 4; ++j4) {
            float4 cc = Crow[j4];
            const int jb = j4 * 4;
            if (cc.x < bm) { bm = cc.x; barg = jb + 0; }
            if (cc.y < bm) { bm = cc.y; barg = jb + 1; }
            if (cc.z < bm) { bm = cc.z; barg = jb + 2; }
            if (cc.w < bm) { bm = cc.w; barg = jb + 3; }
        }
        u[tid]      = bm;   // feasible: C - u - 0 >= 0 exactly; matched slack == 0 exactly
        rowArg[tid] = barg;
        col4row[tid] = -1;
    }
    row4col[tid] = -1;         row4col[tid + 256] = -1;
    colBest[tid] = 0x7fffffff; colBest[tid + 256] = 0x7fffffff;
    __syncthreads();
    atomicMin(&colBest[rowArg[tid]], tid);
    __syncthreads();
    {
        const int j = rowArg[tid];
        if (colBest[j] == tid) { col4row[tid] = j; row4col[j] = tid; }
    }
    __syncthreads();

    // ---- Phase C: augmenting searches, wave 0 only (wave-synchronous) ----
    if (tid < 64) {
        const int lane = tid;
        const int laneOff = (lane >> 3) * 68 + (lane & 7) * 8;
        typedef float v2f __attribute__((ext_vector_type(2)));

        float vR[8];
        #pragma unroll
        for (int c = 0; c < 8; ++c) vR[c] = 0.f;

        int tagReg = -1;   // lane-indexed cache tag (slot == lane)
        int rr     = 0;    // wave-uniform round-robin fill pointer

        for (int cur = 0; cur < kNQ; ++cur) {
            if (col4row[cur] >= 0) continue;   // uniform branch

            float spcR[8]; int pathR[8]; float mskA[8]; float frzV[8]; int frzP[8];
            #pragma unroll
            for (int c = 0; c < 8; ++c) {
                spcR[c] = kInf; pathR[c] = -1; mskA[c] = 0.f;
                frzV[c] = 0.f;  frzP[c] = -1;
            }
            unsigned scMask = 0;

            int   i      = cur;
            float minVal = 0.f;
            int   sink   = -1;

            for (int guard = 0; guard < kNT + 2 && sink < 0; ++guard) {
                const float ui = u[i];            // LDS read, overlaps row fetch
                float4 p0, p1;
                const unsigned long long hm = __ballot(tagReg == i);
                if (hm != 0ull) {                 // cache hit (wave-uniform)
                    const int slot = (int)__ffsll(hm) - 1;
                    const float4* lp = (const float4*)&rowCache[slot * kStride + laneOff];
                    p0 = lp[0]; p1 = lp[1];
                } else {                          // miss: global (L2) load + insert
                    const float4* rp = (const float4*)(C + (size_t)i * kNT + lane * 8);
                    p0 = rp[0]; p1 = rp[1];
                    float4* wp = (float4*)&rowCache[rr * kStride + laneOff];
                    wp[0] = p0; wp[1] = p1;       // fire-and-forget (cur rows too:
                    if (lane == rr) tagReg = i;   //  they're re-expanded once matched)
                    rr = rr + 1; if (rr == kSlots) rr = 0;
                }

                // ---- UNMASKED packed relax (value-exact op order) ----
                const v2f cc2[4] = { {p0.x, p0.y}, {p0.z, p0.w},
                                     {p1.x, p1.y}, {p1.z, p1.w} };
                const v2f mv2 = { minVal, minVal };
                const v2f ui2 = { ui, ui };
                float r8[8];
                #pragma unroll
                for (int p = 0; p < 4; ++p) {
                    const v2f vv = { vR[2*p], vR[2*p + 1] };
                    const v2f rp2 = ((mv2 + cc2[p]) - ui2) - vv;
                    r8[2*p] = rp2.x; r8[2*p + 1] = rp2.y;
                }
                #pragma unroll
                for (int c = 0; c < 8; ++c) {
                    const bool lt = r8[c] < spcR[c];
                    spcR[c]  = lt ? r8[c] : spcR[c];
                    pathR[c] = lt ? i : pathR[c];
                }

                // ---- masked local argmin: msk = spc + {0|+inf}, u32 tree ----
                float mskv[8];
                #pragma unroll
                for (int p = 0; p < 4; ++p) {
                    const v2f s2 = { spcR[2*p], spcR[2*p + 1] };
                    const v2f a2 = { mskA[2*p], mskA[2*p + 1] };
                    const v2f m2 = s2 + a2;
                    mskv[2*p] = m2.x; mskv[2*p + 1] = m2.y;
                }
                unsigned sp[8];
                #pragma unroll
                for (int c = 0; c < 8; ++c) sp[c] = __float_as_uint(mskv[c]);
                unsigned mA = sp[1] < sp[0] ? sp[1] : sp[0]; int aA = sp[1] < sp[0] ? 1 : 0;
                unsigned mB = sp[3] < sp[2] ? sp[3] : sp[2]; int aB = sp[3] < sp[2] ? 3 : 2;
                unsigned mC = sp[5] < sp[4] ? sp[5] : sp[4]; int aC = sp[5] < sp[4] ? 5 : 4;
                unsigned mD = sp[7] < sp[6] ? sp[7] : sp[6]; int aD = sp[7] < sp[6] ? 7 : 6;
                unsigned mAB = mB < mA ? mB : mA; int aAB = mB < mA ? aB : aA;
                unsigned mCD = mD < mC ? mD : mC; int aCD = mD < mC ? aD : aC;
                unsigned lvu = mCD < mAB ? mCD : mAB; int lc = mCD < mAB ? aCD : aAB;
                const int lix  = lane * 8 + lc;
                const int spec = row4col[lix];          // speculative owner prefetch
                const int pk   = ((spec + 1) << 16) | lix;  // one-readlane pack

                const unsigned gmu = wave_min_u32(lvu); // hides the LDS read above
                const unsigned long long bal = __ballot(lvu == gmu);
                const int wl    = (int)__ffsll(bal) - 1;
                const int comb  = __builtin_amdgcn_readlane(pk, wl);
                const int jstar = comb & 0xffff;
                const int own   = (comb >> 16) - 1;
                minVal = __uint_as_float(gmu);

                if (own < 0) sink = jstar;
                else         i    = own;

                if (wl == lane) {                 // freeze sweep-time state
                    const int lcw = jstar & 7;
                    scMask |= 1u << lcw;
                    #pragma unroll
                    for (int c = 0; c < 8; ++c) {
                        if (c == lcw) {
                            mskA[c] = __builtin_inff();
                            frzV[c] = minVal;     // == spcR[c] at sweep time
                            frzP[c] = pathR[c];
                        }
                    }
                }
            }

            // ---- dual updates (sweep-time values, per swept column) ----
            if (lane == 0) u[cur] += minVal;
            #pragma unroll
            for (int c = 0; c < 8; ++c) {
                if ((scMask >> c) & 1u) {
                    const int j = lane * 8 + c;
                    const int r = row4col[j];
                    const float d = minVal - frzV[c];
                    if (r >= 0) u[r] += d;   // owners distinct (matching invariant)
                    vR[c] -= d;
                    pathL[j] = frzP[c];
                }
            }
            __threadfence_block();

            // ---- augment along alternating path (lane 0) ----
            if (lane == 0 && sink >= 0) {
                int j = sink;
                while (true) {
                    const int pi = pathL[j];
                    row4col[j] = pi;
                    const int nj = col4row[pi];
                    col4row[pi] = j;
                    if (pi == cur) break;
                    j = nj;
                }
            }
            __threadfence_block();
        }
    }
    __syncthreads();

    outInds[(size_t)b * kNQ + tid] = (float)col4row[tid];
    outMask[(size_t)b * kNQ + tid] = 1.0f;
}

extern "C" void kernel_launch(void* const* d_in, const int* in_sizes, int n_in,
                              void* d_out, int out_size, void* d_ws, size_t ws_size,
                              hipStream_t stream) {
    const float* trans = (const float*)d_in[0];
    const float* qpos  = (const float*)d_in[1];
    const float* rot   = (const float*)d_in[2];
    const float* pose  = (const float*)d_in[3];

    float* out  = (float*)d_out;
    float* cost = out;
    float* inds = out + (size_t)kB * kNQ * kNT;
    float* mask = inds + (size_t)kB * kNQ;

    dim3 g1(kB, kNQ / kQTile);
    cost_kernel<<<g1, 512, 0, stream>>>(trans, qpos, rot, pose, cost);
    hungarian_kernel<<<kB, 256, 0, stream>>>(cost, inds, mask);
}

// Round 15
// 433.050 us; speedup vs baseline: 2.2993x; 1.0464x over previous
//
#include <hip/hip_runtime.h>

constexpr int kB  = 32;
constexpr int kNQ = 256;   // rows n
constexpr int kNT = 512;   // cols m
constexpr float kInf = 1e30f;
constexpr int kQTile = 32;    // queries per cost block
constexpr int kSlots = 56;    // LDS row-cache entries
constexpr int kStride = 544;  // 8 groups x (64 data + 4 pad) floats

// ---------------------------------------------------------------------------
// Kernel 1: final_cost [B, NQ, NT]. 512 thr/block, thread == target t.
// (proven passing, bit-identical math across all passing rounds)
// ---------------------------------------------------------------------------
__global__ __launch_bounds__(512)
void cost_kernel(const float* __restrict__ trans,
                 const float* __restrict__ qpos,
                 const float* __restrict__ rot,
                 const float* __restrict__ pose,
                 float* __restrict__ cost)
{
    __shared__ float sPose[kNT * 23];   // 47104 B

    const int b     = blockIdx.x;
    const int qBase = blockIdx.y * kQTile;
    const int tid   = threadIdx.x;      // target index t

    const float* pb = pose + (size_t)b * kNT * 23;
    for (int idx = tid; idx < kNT * 23; idx += 512) sPose[idx] = pb[idx];
    __syncthreads();

    float T[23];
    #pragma unroll
    for (int d = 0; d < 23; ++d) T[d] = sPose[tid * 23 + d];

    float s = 0.f;
    #pragma unroll
    for (int d = 0; d < 23; ++d) s += fabsf(T[d]);
    const bool valid = (s > 0.f);

    const float* tr = trans + ((size_t)b * kNQ + qBase) * 3;
    const float* qp = qpos  + ((size_t)b * kNQ + qBase) * 16;
    const float* rt = rot   + ((size_t)b * kNQ + qBase) * 4;
    float* cb = cost + ((size_t)b * kNQ + qBase) * kNT + tid;

    for (int q = 0; q < kQTile; ++q) {
        const float Q0 = tr[q * 3 + 0], Q1 = tr[q * 3 + 1], Q2 = tr[q * 3 + 2];
        float a = fabsf(Q0 - T[0]);
        a += fabsf(Q1 - T[1]);
        a += fabsf(Q2 - T[2]);
        float bsum = 0.f;
        #pragma unroll
        for (int d = 0; d < 16; ++d) bsum += fabsf(qp[q * 16 + d] - T[3 + d]);
        const float r0 = rt[q * 4 + 0], r1 = rt[q * 4 + 1];
        const float r2 = rt[q * 4 + 2], r3 = rt[q * 4 + 3];
        float dot = r0 * T[19] + r1 * T[20] + r2 * T[21] + r3 * T[22];
        float c = (a + bsum) + (1.0f - fabsf(dot));
        cb[(size_t)q * kNT] = valid ? c : kInf;
    }
}

// Wave64 min-reduction via DPP (rocPRIM pattern). All inputs are non-negative
// float bit-patterns (incl +inf sentinel), so u32 order == f32 order.
__device__ __forceinline__ unsigned wave_min_u32(unsigned x) {
    unsigned t;
    t = (unsigned)__builtin_amdgcn_update_dpp((int)0xFFFFFFFF, (int)x, 0x111, 0xF, 0xF, false); x = t < x ? t : x; // row_shr:1
    t = (unsigned)__builtin_amdgcn_update_dpp((int)0xFFFFFFFF, (int)x, 0x112, 0xF, 0xF, false); x = t < x ? t : x; // row_shr:2
    t = (unsigned)__builtin_amdgcn_update_dpp((int)0xFFFFFFFF, (int)x, 0x114, 0xF, 0xF, false); x = t < x ? t : x; // row_shr:4
    t = (unsigned)__builtin_amdgcn_update_dpp((int)0xFFFFFFFF, (int)x, 0x118, 0xF, 0xF, false); x = t < x ? t : x; // row_shr:8
    t = (unsigned)__builtin_amdgcn_update_dpp((int)0xFFFFFFFF, (int)x, 0x142, 0xF, 0xF, false); x = t < x ? t : x; // row_bcast:15
    t = (unsigned)__builtin_amdgcn_update_dpp((int)0xFFFFFFFF, (int)x, 0x143, 0xF, 0xF, false); x = t < x ? t : x; // row_bcast:31
    return (unsigned)__builtin_amdgcn_readlane((int)x, 63);
}

// ---------------------------------------------------------------------------
// Kernel 2: JV LSAP — R11 VERBATIM (best measured: hungarian 357 µs).
// v=0, u=row-min, greedy argmin match (matched slack exactly 0 in fp);
// wave-0 SAP: unmasked packed relax + frozen-at-sweep state, DPP u32 min +
// ballot lowest-lane tie-break, speculative row4col prefetch, padded AoS
// LDS row cache (56 slots, one-shot cur rows NOT inserted).
// ---------------------------------------------------------------------------
__global__ __launch_bounds__(256)
void hungarian_kernel(const float* __restrict__ cost,
                      float* __restrict__ outInds,
                      float* __restrict__ outMask)
{
    __shared__ float rowCache[kSlots * kStride];  // 121856 B
    __shared__ float u[kNQ];
    __shared__ int   col4row[kNQ];
    __shared__ int   row4col[kNT];
    __shared__ int   colBest[kNT];
    __shared__ int   pathL[kNT];
    __shared__ int   rowArg[kNQ];

    const int b   = blockIdx.x;
    const int tid = threadIdx.x;
    const float* __restrict__ C = cost + (size_t)b * kNQ * kNT;

    // ---- Phase A: row minima + greedy matching (thread t == row t) ----
    {
        const float4* Crow = (const float4*)(C + (size_t)tid * kNT);
        float bm = kInf; int barg = 0;
        #pragma unroll 4
        for (int j4 = 0; j4 < kNT / 4; ++j4) {
            float4 cc = Crow[j4];
            const int jb = j4 * 4;
            if (cc.x < bm) { bm = cc.x; barg = jb + 0; }
            if (cc.y < bm) { bm = cc.y; barg = jb + 1; }
            if (cc.z < bm) { bm = cc.z; barg = jb + 2; }
            if (cc.w < bm) { bm = cc.w; barg = jb + 3; }
        }
        u[tid]      = bm;   // feasible: C - u - 0 >= 0 exactly; matched slack == 0 exactly
        rowArg[tid] = barg;
        col4row[tid] = -1;
    }
    row4col[tid] = -1;         row4col[tid + 256] = -1;
    colBest[tid] = 0x7fffffff; colBest[tid + 256] = 0x7fffffff;
    __syncthreads();
    atomicMin(&colBest[rowArg[tid]], tid);
    __syncthreads();
    {
        const int j = rowArg[tid];
        if (colBest[j] == tid) { col4row[tid] = j; row4col[j] = tid; }
    }
    __syncthreads();

    // ---- Phase C: augmenting searches, wave 0 only (wave-synchronous) ----
    if (tid < 64) {
        const int lane = tid;
        const int laneOff = (lane >> 3) * 68 + (lane & 7) * 8;
        typedef float v2f __attribute__((ext_vector_type(2)));

        float vR[8];
        #pragma unroll
        for (int c = 0; c < 8; ++c) vR[c] = 0.f;

        int tagReg = -1;   // lane-indexed cache tag (slot == lane)
        int rr     = 0;    // wave-uniform round-robin fill pointer

        for (int cur = 0; cur < kNQ; ++cur) {
            if (col4row[cur] >= 0) continue;   // uniform branch

            float spcR[8]; int pathR[8]; float mskA[8]; float frzV[8]; int frzP[8];
            #pragma unroll
            for (int c = 0; c < 8; ++c) {
                spcR[c] = kInf; pathR[c] = -1; mskA[c] = 0.f;
                frzV[c] = 0.f;  frzP[c] = -1;
            }
            unsigned scMask = 0;

            int   i      = cur;
            float minVal = 0.f;
            int   sink   = -1;

            for (int guard = 0; guard < kNT + 2 && sink < 0; ++guard) {
                const float ui = u[i];            // LDS read, overlaps row fetch
                float4 p0, p1;
                const unsigned long long hm = __ballot(tagReg == i);
                if (hm != 0ull) {                 // cache hit (wave-uniform)
                    const int slot = (int)__ffsll(hm) - 1;
                    const float4* lp = (const float4*)&rowCache[slot * kStride + laneOff];
                    p0 = lp[0]; p1 = lp[1];
                } else {                          // miss: global (L2) load
                    const float4* rp = (const float4*)(C + (size_t)i * kNT + lane * 8);
                    p0 = rp[0]; p1 = rp[1];
                    if (guard != 0) {             // don't cache one-shot cur rows
                        float4* wp = (float4*)&rowCache[rr * kStride + laneOff];
                        wp[0] = p0; wp[1] = p1;   // fire-and-forget
                        if (lane == rr) tagReg = i;
                        rr = rr + 1; if (rr == kSlots) rr = 0;
                    }
                }

                // ---- UNMASKED packed relax (value-exact op order) ----
                const v2f cc2[4] = { {p0.x, p0.y}, {p0.z, p0.w},
                                     {p1.x, p1.y}, {p1.z, p1.w} };
                const v2f mv2 = { minVal, minVal };
                const v2f ui2 = { ui, ui };
                float r8[8];
                #pragma unroll
                for (int p = 0; p < 4; ++p) {
                    const v2f vv = { vR[2*p], vR[2*p + 1] };
                    const v2f rp2 = ((mv2 + cc2[p]) - ui2) - vv;
                    r8[2*p] = rp2.x; r8[2*p + 1] = rp2.y;
                }
                #pragma unroll
                for (int c = 0; c < 8; ++c) {
                    const bool lt = r8[c] < spcR[c];
                    spcR[c]  = lt ? r8[c] : spcR[c];
                    pathR[c] = lt ? i : pathR[c];
                }

                // ---- masked local argmin: msk = spc + {0|+inf}, u32 tree ----
                float mskv[8];
                #pragma unroll
                for (int p = 0; p < 4; ++p) {
                    const v2f s2 = { spcR[2*p], spcR[2*p + 1] };
                    const v2f a2 = { mskA[2*p], mskA[2*p + 1] };
                    const v2f m2 = s2 + a2;
                    mskv[2*p] = m2.x; mskv[2*p + 1] = m2.y;
                }
                unsigned sp[8];
                #pragma unroll
                for (int c = 0; c < 8; ++c) sp[c] = __float_as_uint(mskv[c]);
                unsigned mA = sp[1] < sp[0] ? sp[1] : sp[0]; int aA = sp[1] < sp[0] ? 1 : 0;
                unsigned mB = sp[3] < sp[2] ? sp[3] : sp[2]; int aB = sp[3] < sp[2] ? 3 : 2;
                unsigned mC = sp[5] < sp[4] ? sp[5] : sp[4]; int aC = sp[5] < sp[4] ? 5 : 4;
                unsigned mD = sp[7] < sp[6] ? sp[7] : sp[6]; int aD = sp[7] < sp[6] ? 7 : 6;
                unsigned mAB = mB < mA ? mB : mA; int aAB = mB < mA ? aB : aA;
                unsigned mCD = mD < mC ? mD : mC; int aCD = mD < mC ? aD : aC;
                unsigned lvu = mCD < mAB ? mCD : mAB; int lc = mCD < mAB ? aCD : aAB;
                const int lix  = lane * 8 + lc;
                const int spec = row4col[lix];          // speculative owner prefetch

                const unsigned gmu = wave_min_u32(lvu); // hides the LDS read above
                const unsigned long long bal = __ballot(lvu == gmu);
                const int wl    = (int)__ffsll(bal) - 1;
                const int jstar = __builtin_amdgcn_readlane(lix, wl);
                const int own   = __builtin_amdgcn_readlane(spec, wl);
                minVal = __uint_as_float(gmu);

                if (own < 0) sink = jstar;
                else         i    = own;

                if (wl == lane) {                 // freeze sweep-time state
                    const int lcw = jstar & 7;
                    scMask |= 1u << lcw;
                    #pragma unroll
                    for (int c = 0; c < 8; ++c) {
                        if (c == lcw) {
                            mskA[c] = __builtin_inff();
                            frzV[c] = minVal;     // == spcR[c] at sweep time
                            frzP[c] = pathR[c];
                        }
                    }
                }
            }

            // ---- dual updates (sweep-time values, per swept column) ----
            if (lane == 0) u[cur] += minVal;
            #pragma unroll
            for (int c = 0; c < 8; ++c) {
                if ((scMask >> c) & 1u) {
                    const int j = lane * 8 + c;
                    const int r = row4col[j];
                    const float d = minVal - frzV[c];
                    if (r >= 0) u[r] += d;   // owners distinct (matching invariant)
                    vR[c] -= d;
                    pathL[j] = frzP[c];
                }
            }
            __threadfence_block();

            // ---- augment along alternating path (lane 0) ----
            if (lane == 0 && sink >= 0) {
                int j = sink;
                while (true) {
                    const int pi = pathL[j];
                    row4col[j] = pi;
                    const int nj = col4row[pi];
                    col4row[pi] = j;
                    if (pi == cur) break;
                    j = nj;
                }
            }
            __threadfence_block();
        }
    }
    __syncthreads();

    outInds[(size_t)b * kNQ + tid] = (float)col4row[tid];
    outMask[(size_t)b * kNQ + tid] = 1.0f;
}

extern "C" void kernel_launch(void* const* d_in, const int* in_sizes, int n_in,
                              void* d_out, int out_size, void* d_ws, size_t ws_size,
                              hipStream_t stream) {
    const float* trans = (const float*)d_in[0];
    const float* qpos  = (const float*)d_in[1];
    const float* rot   = (const float*)d_in[2];
    const float* pose  = (const float*)d_in[3];

    float* out  = (float*)d_out;
    float* cost = out;
    float* inds = out + (size_t)kB * kNQ * kNT;
    float* mask = inds + (size_t)kB * kNQ;

    dim3 g1(kB, kNQ / kQTile);
    cost_kernel<<<g1, 512, 0, stream>>>(trans, qpos, rot, pose, cost);
    hungarian_kernel<<<kB, 256, 0, stream>>>(cost, inds, mask);
}